// Round 5
// baseline (228.608 us; speedup 1.0000x reference)
//
#include <hip/hip_runtime.h>

#define B_ 4
#define H_ 16
#define S_ 1024
#define D_ 64
#define NEGV -1000000000.0f

typedef __bf16 bf16x8 __attribute__((ext_vector_type(8)));
typedef __bf16 bf16x4 __attribute__((ext_vector_type(4)));
typedef float f32x4 __attribute__((ext_vector_type(4)));

__device__ __forceinline__ bf16x8 cvt8(const float* p) {
  float4 x = *(const float4*)p;
  float4 y = *(const float4*)(p + 4);
  bf16x8 f;
  f[0]=(__bf16)x.x; f[1]=(__bf16)x.y; f[2]=(__bf16)x.z; f[3]=(__bf16)x.w;
  f[4]=(__bf16)y.x; f[5]=(__bf16)y.y; f[6]=(__bf16)y.z; f[7]=(__bf16)y.w;
  return f;
}

// ---------------- prep: K f32 -> Kb (bf16 [B,H,S,D]), V f32 -> Vt (bf16 [B,H,D,S]) ----------------
__global__ __launch_bounds__(256) void prep_kernel(
    const float* __restrict__ K, const float* __restrict__ V,
    __bf16* __restrict__ Kb, __bf16* __restrict__ Vt)
{
  int bid = blockIdx.x;            // B*H*16 blocks, each a 64-row s-chunk
  int sc = bid & 15;
  int bh = bid >> 4;
  int tid = threadIdx.x;
  __shared__ float s_v[64][65];

  const float* Kc = K + ((size_t)bh*S_ + sc*64)*D_;
  const float* Vc = V + ((size_t)bh*S_ + sc*64)*D_;
  __bf16* Kbc = Kb + ((size_t)bh*S_ + sc*64)*D_;

  {
    const float4* src = (const float4*)Kc + tid*4;
    float4 a = src[0], b = src[1], c = src[2], d = src[3];
    bf16x8 o0, o1;
    o0[0]=(__bf16)a.x; o0[1]=(__bf16)a.y; o0[2]=(__bf16)a.z; o0[3]=(__bf16)a.w;
    o0[4]=(__bf16)b.x; o0[5]=(__bf16)b.y; o0[6]=(__bf16)b.z; o0[7]=(__bf16)b.w;
    o1[0]=(__bf16)c.x; o1[1]=(__bf16)c.y; o1[2]=(__bf16)c.z; o1[3]=(__bf16)c.w;
    o1[4]=(__bf16)d.x; o1[5]=(__bf16)d.y; o1[6]=(__bf16)d.z; o1[7]=(__bf16)d.w;
    *(bf16x8*)(Kbc + tid*16)     = o0;
    *(bf16x8*)(Kbc + tid*16 + 8) = o1;
  }
  for (int i = tid; i < 64*16; i += 256) {
    int r = i >> 4, c4 = i & 15;
    float4 v = ((const float4*)(Vc + (size_t)r*D_))[c4];
    s_v[r][c4*4+0] = v.x; s_v[r][c4*4+1] = v.y;
    s_v[r][c4*4+2] = v.z; s_v[r][c4*4+3] = v.w;
  }
  __syncthreads();
  {
    int d = tid >> 2, seg = tid & 3;
    bf16x8 o0, o1;
    #pragma unroll
    for (int j = 0; j < 8; ++j) o0[j] = (__bf16)s_v[seg*16 + j][d];
    #pragma unroll
    for (int j = 0; j < 8; ++j) o1[j] = (__bf16)s_v[seg*16 + 8 + j][d];
    __bf16* dst = Vt + ((size_t)bh*D_ + d)*S_ + sc*64 + seg*16;
    *(bf16x8*)dst = o0;
    *(bf16x8*)(dst + 8) = o1;
  }
}

// ---------------- topic: swapped MFMA + in-reg softmax -> signed tp [B,S,S] f32 ----------------
__global__ __launch_bounds__(256) void topic_kernel(
    const float* __restrict__ tq, const float* __restrict__ tk,
    const int* __restrict__ mask, float* __restrict__ tp)
{
  int bid0 = blockIdx.x;                 // 256 = 8 * 32
  int bid = (bid0 & 7)*32 + (bid0 >> 3);
  int qt = bid & 63, b = bid >> 6;
  int tid = threadIdx.x, wave = tid >> 6, lane = tid & 63;
  int l15 = lane & 15, lhi = lane >> 4;
  __shared__ float2 s_red[4][16];

  const int* mb = mask + b*S_;
  bf16x8 qf[2];
  #pragma unroll
  for (int dc = 0; dc < 2; ++dc)
    qf[dc] = cvt8(tq + ((size_t)b*S_ + qt*16 + l15)*D_ + dc*32 + lhi*8);
  int mq = mb[qt*16 + l15];

  f32x4 sc[16];
  #pragma unroll
  for (int kt = 0; kt < 16; ++kt) {
    int kb = wave*256 + kt*16;
    const float* kr = tk + ((size_t)b*S_ + kb + l15)*D_ + lhi*8;
    bf16x8 k0 = cvt8(kr);
    bf16x8 k1 = cvt8(kr + 32);
    f32x4 acc = {0.f,0.f,0.f,0.f};
    acc = __builtin_amdgcn_mfma_f32_16x16x32_bf16(k0, qf[0], acc, 0, 0, 0);
    acc = __builtin_amdgcn_mfma_f32_16x16x32_bf16(k1, qf[1], acc, 0, 0, 0);
    int4 mk = *(const int4*)(mb + kb + lhi*4);
    sc[kt][0] = (mq && mk.x) ? acc[0]*0.125f : 1.0f;
    sc[kt][1] = (mq && mk.y) ? acc[1]*0.125f : 1.0f;
    sc[kt][2] = (mq && mk.z) ? acc[2]*0.125f : 1.0f;
    sc[kt][3] = (mq && mk.w) ? acc[3]*0.125f : 1.0f;
  }
  float m = -3.4e38f;
  #pragma unroll
  for (int kt = 0; kt < 16; ++kt) {
    #pragma unroll
    for (int i = 0; i < 4; ++i) m = fmaxf(m, sc[kt][i]);
  }
  m = fmaxf(m, __shfl_xor(m, 16));
  m = fmaxf(m, __shfl_xor(m, 32));
  float sum = 0.f;
  #pragma unroll
  for (int kt = 0; kt < 16; ++kt) {
    #pragma unroll
    for (int i = 0; i < 4; ++i) { sc[kt][i] = __expf(sc[kt][i] - m); sum += sc[kt][i]; }
  }
  sum += __shfl_xor(sum, 16);
  sum += __shfl_xor(sum, 32);
  if (lane < 16) s_red[wave][l15] = make_float2(m, sum);
  __syncthreads();
  float M = -3.4e38f;
  #pragma unroll
  for (int w = 0; w < 4; ++w) M = fmaxf(M, s_red[w][l15].x);
  float Z = 0.f;
  #pragma unroll
  for (int w = 0; w < 4; ++w) Z += s_red[w][l15].y * __expf(s_red[w][l15].x - M);
  float scale = __expf(m - M) / Z;

  float* tpr = tp + ((size_t)b*S_ + qt*16 + l15)*S_;
  #pragma unroll
  for (int kt = 0; kt < 16; ++kt) {
    int kb = wave*256 + kt*16;
    int4 mk = *(const int4*)(mb + kb + lhi*4);
    f32x4 pv;
    pv[0] = sc[kt][0]*scale; if (!(mq && mk.x)) pv[0] = -pv[0];
    pv[1] = sc[kt][1]*scale; if (!(mq && mk.y)) pv[1] = -pv[1];
    pv[2] = sc[kt][2]*scale; if (!(mq && mk.z)) pv[2] = -pv[2];
    pv[3] = sc[kt][3]*scale; if (!(mq && mk.w)) pv[3] = -pv[3];
    *(f32x4*)(tpr + kb + lhi*4) = pv;
  }
}

// ---------------- attn: swapped QK^T -> in-reg softmax -> PV ----------------
__global__ __launch_bounds__(256) void attn_kernel(
    const float* __restrict__ Q, const __bf16* __restrict__ Kb,
    const __bf16* __restrict__ Vt, const float* __restrict__ tp,
    float* __restrict__ out, float* __restrict__ pa)
{
  int bid0 = blockIdx.x;                 // 4096 = 8 * 512
  int bid = (bid0 & 7)*512 + (bid0 >> 3);
  int qt = bid & 63;
  int h  = (bid >> 6) & 15;
  int b  = bid >> 10;
  int tid = threadIdx.x, wave = tid >> 6, lane = tid & 63;
  int l15 = lane & 15, lhi = lane >> 4;

  __shared__ __bf16 s_p[16*1024];        // P bf16, swizzled: byte = q*2048 + (k*2 ^ ((q&7)<<4))
  __shared__ float2 s_red[4][16];

  size_t bh = (size_t)b*H_ + h;
  const __bf16* Kbh = Kb + bh*S_*D_;
  const float* tpb = tp + ((size_t)b*S_ + qt*16 + l15)*S_;   // this lane's q-row

  bf16x8 qf[2];
  #pragma unroll
  for (int dc = 0; dc < 2; ++dc)
    qf[dc] = cvt8(Q + (bh*S_ + qt*16 + l15)*D_ + dc*32 + lhi*8);

  // ---- QK^T swapped: D[k][q], lane holds q = l15, k = kb + lhi*4 + i ----
  f32x4 sc[16];
  #pragma unroll
  for (int kt = 0; kt < 16; ++kt) {
    int kb = wave*256 + kt*16;
    const __bf16* kr = Kbh + (size_t)(kb + l15)*D_ + lhi*8;
    bf16x8 k0 = *(const bf16x8*)kr;
    bf16x8 k1 = *(const bf16x8*)(kr + 32);
    f32x4 acc = {0.f,0.f,0.f,0.f};
    acc = __builtin_amdgcn_mfma_f32_16x16x32_bf16(k0, qf[0], acc, 0, 0, 0);
    acc = __builtin_amdgcn_mfma_f32_16x16x32_bf16(k1, qf[1], acc, 0, 0, 0);
    float4 t = *(const float4*)(tpb + kb + lhi*4);
    sc[kt][0] = (t.x > 0.f) ? acc[0]*0.125f*t.x : NEGV*(-t.x);
    sc[kt][1] = (t.y > 0.f) ? acc[1]*0.125f*t.y : NEGV*(-t.y);
    sc[kt][2] = (t.z > 0.f) ? acc[2]*0.125f*t.z : NEGV*(-t.z);
    sc[kt][3] = (t.w > 0.f) ? acc[3]*0.125f*t.w : NEGV*(-t.w);
  }

  // ---- in-register softmax over k ----
  float m = -3.4e38f;
  #pragma unroll
  for (int kt = 0; kt < 16; ++kt) {
    #pragma unroll
    for (int i = 0; i < 4; ++i) m = fmaxf(m, sc[kt][i]);
  }
  m = fmaxf(m, __shfl_xor(m, 16));
  m = fmaxf(m, __shfl_xor(m, 32));
  float sum = 0.f;
  #pragma unroll
  for (int kt = 0; kt < 16; ++kt) {
    #pragma unroll
    for (int i = 0; i < 4; ++i) { sc[kt][i] = __expf(sc[kt][i] - m); sum += sc[kt][i]; }
  }
  sum += __shfl_xor(sum, 16);
  sum += __shfl_xor(sum, 32);
  if (lane < 16) s_red[wave][l15] = make_float2(m, sum);
  __syncthreads();
  float M = -3.4e38f;
  #pragma unroll
  for (int w = 0; w < 4; ++w) M = fmaxf(M, s_red[w][l15].x);
  float Z = 0.f;
  #pragma unroll
  for (int w = 0; w < 4; ++w) Z += s_red[w][l15].y * __expf(s_red[w][l15].x - M);
  float scale = __expf(m - M) / Z;

  // ---- write pa (plain f32x4 — L2 write-combines the 64B chunks) + P -> LDS bf16 (swizzled) ----
  float* par = pa + (bh*S_ + qt*16 + l15)*S_;
  #pragma unroll
  for (int kt = 0; kt < 16; ++kt) {
    int kb = wave*256 + kt*16;
    f32x4 pv;
    pv[0] = sc[kt][0]*scale;
    pv[1] = sc[kt][1]*scale;
    pv[2] = sc[kt][2]*scale;
    pv[3] = sc[kt][3]*scale;
    *(f32x4*)(par + kb + lhi*4) = pv;
    bf16x4 pb;
    pb[0] = (__bf16)pv[0]; pb[1] = (__bf16)pv[1];
    pb[2] = (__bf16)pv[2]; pb[3] = (__bf16)pv[3];
    *(bf16x4*)((char*)s_p + l15*2048 + ((wave*512 + kt*32 + lhi*8) ^ ((l15 & 7) << 4))) = pb;
  }
  __syncthreads();

  // ---- PV: wave w covers d in [w*16, w*16+16); A from LDS, B from global Vt ----
  const __bf16* Vh = Vt + (bh*D_ + wave*16 + l15)*S_ + lhi*8;
  f32x4 oacc = {0.f,0.f,0.f,0.f};
  #pragma unroll
  for (int ks = 0; ks < 32; ++ks) {
    bf16x8 a  = *(const bf16x8*)((char*)s_p + l15*2048 + ((ks*64 + lhi*16) ^ ((l15 & 7) << 4)));
    bf16x8 bv = *(const bf16x8*)(Vh + ks*32);
    oacc = __builtin_amdgcn_mfma_f32_16x16x32_bf16(a, bv, oacc, 0, 0, 0);
  }
  #pragma unroll
  for (int i = 0; i < 4; ++i)
    __builtin_nontemporal_store(oacc[i], out + (bh*S_ + qt*16 + lhi*4 + i)*D_ + wave*16 + l15);
}

extern "C" void kernel_launch(void* const* d_in, const int* in_sizes, int n_in,
                              void* d_out, int out_size, void* d_ws, size_t ws_size,
                              hipStream_t stream) {
  const float* Q    = (const float*)d_in[0];
  const float* K    = (const float*)d_in[1];
  const float* V    = (const float*)d_in[2];
  const int*   mask = (const int*)d_in[4];
  const float* tq   = (const float*)d_in[5];
  const float* tk   = (const float*)d_in[6];

  // ws layout: tp f32 [B,S,S] = 16MB | Kb bf16 [B,H,S,D] = 8MB | Vt bf16 [B,H,D,S] = 8MB
  float*  tp = (float*)d_ws;
  __bf16* Kb = (__bf16*)((char*)d_ws + (size_t)B_*S_*S_*4);
  __bf16* Vt = Kb + (size_t)B_*H_*S_*D_;

  float* outp = (float*)d_out;                      // [B,H,S,D]
  float* pa   = outp + (size_t)B_*H_*S_*D_;         // [B,H,S,S]

  prep_kernel <<<B_*H_*16, 256, 0, stream>>>(K, V, Kb, Vt);
  topic_kernel<<<B_*64,    256, 0, stream>>>(tq, tk, mask, tp);
  attn_kernel <<<B_*H_*64, 256, 0, stream>>>(Q, Kb, Vt, tp, outp, pa);
}

// Round 6
// 197.646 us; speedup vs baseline: 1.1567x; 1.1567x over previous
//
#include <hip/hip_runtime.h>

#define B_ 4
#define H_ 16
#define S_ 1024
#define D_ 64
#define NEGV -1000000000.0f

typedef __bf16 bf16x8 __attribute__((ext_vector_type(8)));
typedef __bf16 bf16x4 __attribute__((ext_vector_type(4)));
typedef float f32x4 __attribute__((ext_vector_type(4)));

__device__ __forceinline__ bf16x8 cvt8(const float* p) {
  float4 x = *(const float4*)p;
  float4 y = *(const float4*)(p + 4);
  bf16x8 f;
  f[0]=(__bf16)x.x; f[1]=(__bf16)x.y; f[2]=(__bf16)x.z; f[3]=(__bf16)x.w;
  f[4]=(__bf16)y.x; f[5]=(__bf16)y.y; f[6]=(__bf16)y.z; f[7]=(__bf16)y.w;
  return f;
}

// ---------------- prep: K f32 -> Kb (bf16 [B,H,S,D]), V f32 -> Vt (bf16 [B,H,D,S]) ----------------
__global__ __launch_bounds__(256) void prep_kernel(
    const float* __restrict__ K, const float* __restrict__ V,
    __bf16* __restrict__ Kb, __bf16* __restrict__ Vt)
{
  int bid = blockIdx.x;            // B*H*16 blocks, each a 64-row s-chunk
  int sc = bid & 15;
  int bh = bid >> 4;
  int tid = threadIdx.x;
  __shared__ float s_v[64][65];

  const float* Kc = K + ((size_t)bh*S_ + sc*64)*D_;
  const float* Vc = V + ((size_t)bh*S_ + sc*64)*D_;
  __bf16* Kbc = Kb + ((size_t)bh*S_ + sc*64)*D_;

  {
    const float4* src = (const float4*)Kc + tid*4;
    float4 a = src[0], b = src[1], c = src[2], d = src[3];
    bf16x8 o0, o1;
    o0[0]=(__bf16)a.x; o0[1]=(__bf16)a.y; o0[2]=(__bf16)a.z; o0[3]=(__bf16)a.w;
    o0[4]=(__bf16)b.x; o0[5]=(__bf16)b.y; o0[6]=(__bf16)b.z; o0[7]=(__bf16)b.w;
    o1[0]=(__bf16)c.x; o1[1]=(__bf16)c.y; o1[2]=(__bf16)c.z; o1[3]=(__bf16)c.w;
    o1[4]=(__bf16)d.x; o1[5]=(__bf16)d.y; o1[6]=(__bf16)d.z; o1[7]=(__bf16)d.w;
    *(bf16x8*)(Kbc + tid*16)     = o0;
    *(bf16x8*)(Kbc + tid*16 + 8) = o1;
  }
  for (int i = tid; i < 64*16; i += 256) {
    int r = i >> 4, c4 = i & 15;
    float4 v = ((const float4*)(Vc + (size_t)r*D_))[c4];
    s_v[r][c4*4+0] = v.x; s_v[r][c4*4+1] = v.y;
    s_v[r][c4*4+2] = v.z; s_v[r][c4*4+3] = v.w;
  }
  __syncthreads();
  {
    int d = tid >> 2, seg = tid & 3;
    bf16x8 o0, o1;
    #pragma unroll
    for (int j = 0; j < 8; ++j) o0[j] = (__bf16)s_v[seg*16 + j][d];
    #pragma unroll
    for (int j = 0; j < 8; ++j) o1[j] = (__bf16)s_v[seg*16 + 8 + j][d];
    __bf16* dst = Vt + ((size_t)bh*D_ + d)*S_ + sc*64 + seg*16;
    *(bf16x8*)dst = o0;
    *(bf16x8*)(dst + 8) = o1;
  }
}

// ---------------- topic: swapped MFMA + in-reg softmax -> signed tp [B,S,S] f32 ----------------
__global__ __launch_bounds__(256) void topic_kernel(
    const float* __restrict__ tq, const float* __restrict__ tk,
    const int* __restrict__ mask, float* __restrict__ tp)
{
  int bid0 = blockIdx.x;                 // 256 = 8 * 32
  int bid = (bid0 & 7)*32 + (bid0 >> 3);
  int qt = bid & 63, b = bid >> 6;
  int tid = threadIdx.x, wave = tid >> 6, lane = tid & 63;
  int l15 = lane & 15, lhi = lane >> 4;
  __shared__ float2 s_red[4][16];
  __shared__ __align__(16) char s_mem[4*8704];   // per-wave f32 transpose scratch [16][136]

  const int* mb = mask + b*S_;
  bf16x8 qf[2];
  #pragma unroll
  for (int dc = 0; dc < 2; ++dc)
    qf[dc] = cvt8(tq + ((size_t)b*S_ + qt*16 + l15)*D_ + dc*32 + lhi*8);
  int mq = mb[qt*16 + l15];

  f32x4 sc[16];
  #pragma unroll
  for (int kt = 0; kt < 16; ++kt) {
    int kb = wave*256 + kt*16;
    const float* kr = tk + ((size_t)b*S_ + kb + l15)*D_ + lhi*8;
    bf16x8 k0 = cvt8(kr);
    bf16x8 k1 = cvt8(kr + 32);
    f32x4 acc = {0.f,0.f,0.f,0.f};
    acc = __builtin_amdgcn_mfma_f32_16x16x32_bf16(k0, qf[0], acc, 0, 0, 0);
    acc = __builtin_amdgcn_mfma_f32_16x16x32_bf16(k1, qf[1], acc, 0, 0, 0);
    int4 mk = *(const int4*)(mb + kb + lhi*4);
    sc[kt][0] = (mq && mk.x) ? acc[0]*0.125f : 1.0f;
    sc[kt][1] = (mq && mk.y) ? acc[1]*0.125f : 1.0f;
    sc[kt][2] = (mq && mk.z) ? acc[2]*0.125f : 1.0f;
    sc[kt][3] = (mq && mk.w) ? acc[3]*0.125f : 1.0f;
  }
  float m = -3.4e38f;
  #pragma unroll
  for (int kt = 0; kt < 16; ++kt) {
    #pragma unroll
    for (int i = 0; i < 4; ++i) m = fmaxf(m, sc[kt][i]);
  }
  m = fmaxf(m, __shfl_xor(m, 16));
  m = fmaxf(m, __shfl_xor(m, 32));
  float sum = 0.f;
  #pragma unroll
  for (int kt = 0; kt < 16; ++kt) {
    #pragma unroll
    for (int i = 0; i < 4; ++i) { sc[kt][i] = __expf(sc[kt][i] - m); sum += sc[kt][i]; }
  }
  sum += __shfl_xor(sum, 16);
  sum += __shfl_xor(sum, 32);
  if (lane < 16) s_red[wave][l15] = make_float2(m, sum);
  __syncthreads();
  float M = -3.4e38f;
  #pragma unroll
  for (int w = 0; w < 4; ++w) M = fmaxf(M, s_red[w][l15].x);
  float Z = 0.f;
  #pragma unroll
  for (int w = 0; w < 4; ++w) Z += s_red[w][l15].y * __expf(s_red[w][l15].x - M);
  float scale = __expf(m - M) / Z;

  // apply scale + mask sign in registers
  int mkv[16];
  #pragma unroll
  for (int kt = 0; kt < 16; ++kt) {
    int kb = wave*256 + kt*16;
    int4 mk = *(const int4*)(mb + kb + lhi*4);
    sc[kt][0] *= scale; if (!(mq && mk.x)) sc[kt][0] = -sc[kt][0];
    sc[kt][1] *= scale; if (!(mq && mk.y)) sc[kt][1] = -sc[kt][1];
    sc[kt][2] *= scale; if (!(mq && mk.z)) sc[kt][2] = -sc[kt][2];
    sc[kt][3] *= scale; if (!(mq && mk.w)) sc[kt][3] = -sc[kt][3];
    (void)mkv;
  }

  // transpose via wave-private LDS -> coalesced stores
  float* xw = (float*)s_mem + wave*2176;
  float* tpw = tp + ((size_t)b*S_ + qt*16)*S_ + wave*256;
  #pragma unroll
  for (int h = 0; h < 2; ++h) {
    #pragma unroll
    for (int j = 0; j < 8; ++j)
      *(f32x4*)(xw + l15*136 + j*16 + lhi*4) = sc[h*8 + j];
    __syncthreads();
    #pragma unroll
    for (int rr = 0; rr < 8; ++rr) {
      int r = rr*2 + (lane >> 5);
      f32x4 a = *(f32x4*)(xw + r*136 + (lane & 31)*4);
      *(f32x4*)(tpw + (size_t)r*S_ + h*128 + (lane & 31)*4) = a;
    }
    __syncthreads();
  }
}

// ---------------- attn: swapped QK^T -> in-reg softmax -> transpose-coalesced pa -> PV ----------------
__global__ __launch_bounds__(256) void attn_kernel(
    const float* __restrict__ Q, const __bf16* __restrict__ Kb,
    const __bf16* __restrict__ Vt, const float* __restrict__ tp,
    float* __restrict__ out, float* __restrict__ pa)
{
  int bid0 = blockIdx.x;                 // 4096 = 8 * 512
  int bid = (bid0 & 7)*512 + (bid0 >> 3);
  int qt = bid & 63;
  int h  = (bid >> 6) & 15;
  int b  = bid >> 10;
  int tid = threadIdx.x, wave = tid >> 6, lane = tid & 63;
  int l15 = lane & 15, lhi = lane >> 4;

  // s_mem: first used as per-wave f32 transpose scratch (4 x [16][136] = 34816B),
  // then as bf16 P [16][1024] swizzled (32768B) for PV.
  __shared__ __align__(16) char s_mem[4*8704];
  __shared__ float2 s_red[4][16];

  size_t bh = (size_t)b*H_ + h;
  const __bf16* Kbh = Kb + bh*S_*D_;
  const float* tpb = tp + ((size_t)b*S_ + qt*16 + l15)*S_;   // this lane's q-row

  bf16x8 qf[2];
  #pragma unroll
  for (int dc = 0; dc < 2; ++dc)
    qf[dc] = cvt8(Q + (bh*S_ + qt*16 + l15)*D_ + dc*32 + lhi*8);

  // ---- QK^T swapped: D[k][q], lane holds q = l15, k = kb + lhi*4 + i ----
  f32x4 sc[16];
  #pragma unroll
  for (int kt = 0; kt < 16; ++kt) {
    int kb = wave*256 + kt*16;
    const __bf16* kr = Kbh + (size_t)(kb + l15)*D_ + lhi*8;
    bf16x8 k0 = *(const bf16x8*)kr;
    bf16x8 k1 = *(const bf16x8*)(kr + 32);
    f32x4 acc = {0.f,0.f,0.f,0.f};
    acc = __builtin_amdgcn_mfma_f32_16x16x32_bf16(k0, qf[0], acc, 0, 0, 0);
    acc = __builtin_amdgcn_mfma_f32_16x16x32_bf16(k1, qf[1], acc, 0, 0, 0);
    float4 t = *(const float4*)(tpb + kb + lhi*4);
    sc[kt][0] = (t.x > 0.f) ? acc[0]*0.125f*t.x : NEGV*(-t.x);
    sc[kt][1] = (t.y > 0.f) ? acc[1]*0.125f*t.y : NEGV*(-t.y);
    sc[kt][2] = (t.z > 0.f) ? acc[2]*0.125f*t.z : NEGV*(-t.z);
    sc[kt][3] = (t.w > 0.f) ? acc[3]*0.125f*t.w : NEGV*(-t.w);
  }

  // ---- in-register softmax over k ----
  float m = -3.4e38f;
  #pragma unroll
  for (int kt = 0; kt < 16; ++kt) {
    #pragma unroll
    for (int i = 0; i < 4; ++i) m = fmaxf(m, sc[kt][i]);
  }
  m = fmaxf(m, __shfl_xor(m, 16));
  m = fmaxf(m, __shfl_xor(m, 32));
  float sum = 0.f;
  #pragma unroll
  for (int kt = 0; kt < 16; ++kt) {
    #pragma unroll
    for (int i = 0; i < 4; ++i) { sc[kt][i] = __expf(sc[kt][i] - m); sum += sc[kt][i]; }
  }
  sum += __shfl_xor(sum, 16);
  sum += __shfl_xor(sum, 32);
  if (lane < 16) s_red[wave][l15] = make_float2(m, sum);
  __syncthreads();
  float M = -3.4e38f;
  #pragma unroll
  for (int w = 0; w < 4; ++w) M = fmaxf(M, s_red[w][l15].x);
  float Z = 0.f;
  #pragma unroll
  for (int w = 0; w < 4; ++w) Z += s_red[w][l15].y * __expf(s_red[w][l15].x - M);
  float scale = __expf(m - M) / Z;

  #pragma unroll
  for (int kt = 0; kt < 16; ++kt) {
    #pragma unroll
    for (int i = 0; i < 4; ++i) sc[kt][i] *= scale;
  }

  // ---- pa: transpose via wave-private f32 LDS, then coalesced nontemporal f32x4 stores ----
  float* xw = (float*)s_mem + wave*2176;                       // [16][136]
  float* paw = pa + (bh*S_ + qt*16)*S_ + wave*256;
  #pragma unroll
  for (int hh = 0; hh < 2; ++hh) {
    #pragma unroll
    for (int j = 0; j < 8; ++j)
      *(f32x4*)(xw + l15*136 + j*16 + lhi*4) = sc[hh*8 + j];
    __syncthreads();
    #pragma unroll
    for (int rr = 0; rr < 8; ++rr) {
      int r = rr*2 + (lane >> 5);
      f32x4 a = *(f32x4*)(xw + r*136 + (lane & 31)*4);
      __builtin_nontemporal_store(a, (f32x4*)(paw + (size_t)r*S_ + hh*128 + (lane & 31)*4));
    }
    __syncthreads();
  }

  // ---- P -> bf16 LDS (swizzled), then PV ----
  #pragma unroll
  for (int kt = 0; kt < 16; ++kt) {
    bf16x4 pb;
    pb[0] = (__bf16)sc[kt][0]; pb[1] = (__bf16)sc[kt][1];
    pb[2] = (__bf16)sc[kt][2]; pb[3] = (__bf16)sc[kt][3];
    *(bf16x4*)(s_mem + l15*2048 + ((wave*512 + kt*32 + lhi*8) ^ ((l15 & 7) << 4))) = pb;
  }
  __syncthreads();

  // ---- PV: wave w covers d in [w*16, w*16+16); A from LDS, B from global Vt ----
  const __bf16* Vh = Vt + (bh*D_ + wave*16 + l15)*S_ + lhi*8;
  f32x4 oacc = {0.f,0.f,0.f,0.f};
  #pragma unroll
  for (int ks = 0; ks < 32; ++ks) {
    bf16x8 a  = *(const bf16x8*)(s_mem + l15*2048 + ((ks*64 + lhi*16) ^ ((l15 & 7) << 4)));
    bf16x8 bv = *(const bf16x8*)(Vh + ks*32);
    oacc = __builtin_amdgcn_mfma_f32_16x16x32_bf16(a, bv, oacc, 0, 0, 0);
  }
  #pragma unroll
  for (int i = 0; i < 4; ++i)
    __builtin_nontemporal_store(oacc[i], out + (bh*S_ + qt*16 + lhi*4 + i)*D_ + wave*16 + l15);
}

extern "C" void kernel_launch(void* const* d_in, const int* in_sizes, int n_in,
                              void* d_out, int out_size, void* d_ws, size_t ws_size,
                              hipStream_t stream) {
  const float* Q    = (const float*)d_in[0];
  const float* K    = (const float*)d_in[1];
  const float* V    = (const float*)d_in[2];
  const int*   mask = (const int*)d_in[4];
  const float* tq   = (const float*)d_in[5];
  const float* tk   = (const float*)d_in[6];

  // ws layout: tp f32 [B,S,S] = 16MB | Kb bf16 [B,H,S,D] = 8MB | Vt bf16 [B,H,D,S] = 8MB
  float*  tp = (float*)d_ws;
  __bf16* Kb = (__bf16*)((char*)d_ws + (size_t)B_*S_*S_*4);
  __bf16* Vt = Kb + (size_t)B_*H_*S_*D_;

  float* outp = (float*)d_out;                      // [B,H,S,D]
  float* pa   = outp + (size_t)B_*H_*S_*D_;         // [B,H,S,S]

  prep_kernel <<<B_*H_*16, 256, 0, stream>>>(K, V, Kb, Vt);
  topic_kernel<<<B_*64,    256, 0, stream>>>(tq, tk, mask, tp);
  attn_kernel <<<B_*H_*64, 256, 0, stream>>>(Q, Kb, Vt, tp, outp, pa);
}